// Round 5
// baseline (209.407 us; speedup 1.0000x reference)
//
#include <hip/hip_runtime.h>

#define BB 2
#define NN 384
#define CC 1024
#define HR 256      // H_REPN
#define NHEADS 4
#define TOPK 8
#define CAP 448
#define NEG 0.2f

typedef __attribute__((ext_vector_type(8))) short bf16x8;
typedef __attribute__((ext_vector_type(4))) float f32x4;

__device__ __forceinline__ unsigned short f2bf(float v) {
    unsigned u = __float_as_uint(v);
    return (unsigned short)((u + 0x7FFFu + ((u >> 16) & 1u)) >> 16);
}
__device__ __forceinline__ float bf2f(unsigned short h) {
    return __uint_as_float((unsigned)h << 16);
}

// ---------------- merged prep: Asw, Bsw, Ah/Al, Bh/Bl, wgp, zero counts ----------------
// block ranges: [0,396) prepa | [396,924) prepb-tiled | [924,1308) prepa2 | [1308,1564) prepb2-tiled | 1564 wgp
__global__ __launch_bounds__(256) void k_prep(const float* __restrict__ feats,
        const float* __restrict__ boxes, const float* __restrict__ gat1_w,
        const float* __restrict__ fc1_w,
        uint4* __restrict__ Asw, uint4* __restrict__ Bsw,
        uint4* __restrict__ Ah, uint4* __restrict__ Al,
        uint4* __restrict__ Bh, uint4* __restrict__ Bl,
        float4* __restrict__ wgp, int* __restrict__ counts) {
    __shared__ float sw[32][65];
    int blk = blockIdx.x;
    int t = threadIdx.x;
    int gflat = blk * 256 + t;
    if (gflat < BB * NN) counts[gflat] = 0;

    if (blk < 396) {                    // ---- prep A for xw1 (Kp=1056), contiguous reads ----
        int flat = gflat;
        int lane = flat & 63;
        int kc = (flat >> 6) % 33;
        int mt = flat / (33 * 64);
        int m = mt * 16 + (lane & 15);
        int k0 = kc * 32 + (lane >> 4) * 8;
        unsigned short vals[8];
        const float s = 1.0f / 800.0f;
#pragma unroll
        for (int j = 0; j < 8; j++) {
            int k = k0 + j;
            float v;
            if (k < CC) v = feats[(size_t)m * CC + k];
            else if (k < CC + 4) {
                const float* bx = boxes + (size_t)m * 4;
                int gk = k - CC;
                v = (gk == 0) ? bx[0] * s : (gk == 1) ? bx[1] * s
                  : (gk == 2) ? (bx[2] - bx[0]) * s : (bx[3] - bx[1]) * s;
            } else v = 0.f;
            vals[j] = f2bf(v);
        }
        uint4 pk;
        pk.x = (unsigned)vals[0] | ((unsigned)vals[1] << 16);
        pk.y = (unsigned)vals[2] | ((unsigned)vals[3] << 16);
        pk.z = (unsigned)vals[4] | ((unsigned)vals[5] << 16);
        pk.w = (unsigned)vals[6] | ((unsigned)vals[7] << 16);
        Asw[flat] = pk;
    } else if (blk < 924) {             // ---- prep B for xw1 (gat1_w) via LDS tile, coalesced ----
        int blkrel = blk - 396;          // ntg*33 + kc ; ntg in [0,16), kc in [0,33)
        int ntg = blkrel / 33;
        int kc  = blkrel % 33;
        int k0 = kc * 32;
        int n0 = ntg * 64;
        // load 32 x 64 tile coalesced (4 rows per pass)
#pragma unroll
        for (int pass = 0; pass < 8; pass++) {
            int kl = pass * 4 + (t >> 6);
            int k = k0 + kl;
            int nl = t & 63;
            float v = (k < CC + 4) ? gat1_w[(size_t)k * 1024 + n0 + nl] : 0.f;
            sw[kl][nl] = v;
        }
        __syncthreads();
        int local_nt = t >> 6;           // 0..3
        int lane = t & 63;
        int nn = lane & 15;
        int q = lane >> 4;
        int nl = local_nt * 16 + nn;
        unsigned short vals[8];
#pragma unroll
        for (int j = 0; j < 8; j++) vals[j] = f2bf(sw[q * 8 + j][nl]);
        uint4 pk;
        pk.x = (unsigned)vals[0] | ((unsigned)vals[1] << 16);
        pk.y = (unsigned)vals[2] | ((unsigned)vals[3] << 16);
        pk.z = (unsigned)vals[4] | ((unsigned)vals[5] << 16);
        pk.w = (unsigned)vals[6] | ((unsigned)vals[7] << 16);
        int nt = ntg * 4 + local_nt;
        Bsw[(size_t)nt * 33 * 64 + kc * 64 + lane] = pk;
    } else if (blk < 1308) {            // ---- prep A hi/lo for p12 (feats), contiguous reads ----
        int flat = gflat - 924 * 256;
        int lane = flat & 63;
        int kc = (flat >> 6) % 32;
        int mt = flat / (32 * 64);
        int m = mt * 16 + (lane & 15);
        int k0 = kc * 32 + (lane >> 4) * 8;
        unsigned short vh[8], vl[8];
        const float* src = feats + (size_t)m * CC + k0;
#pragma unroll
        for (int j = 0; j < 8; j++) {
            float v = src[j];
            unsigned short h = f2bf(v);
            vh[j] = h;
            vl[j] = f2bf(v - bf2f(h));
        }
        uint4 ph, pl;
        ph.x = (unsigned)vh[0] | ((unsigned)vh[1] << 16);
        ph.y = (unsigned)vh[2] | ((unsigned)vh[3] << 16);
        ph.z = (unsigned)vh[4] | ((unsigned)vh[5] << 16);
        ph.w = (unsigned)vh[6] | ((unsigned)vh[7] << 16);
        pl.x = (unsigned)vl[0] | ((unsigned)vl[1] << 16);
        pl.y = (unsigned)vl[2] | ((unsigned)vl[3] << 16);
        pl.z = (unsigned)vl[4] | ((unsigned)vl[5] << 16);
        pl.w = (unsigned)vl[6] | ((unsigned)vl[7] << 16);
        Ah[flat] = ph; Al[flat] = pl;
    } else if (blk < 1564) {            // ---- prep B hi/lo for p12 ([Wa|Wb]) via LDS tile ----
        int blkrel = blk - 1308;         // ntg*32 + kc ; ntg in [0,8), kc in [0,32)
        int ntg = blkrel / 32;
        int kc  = blkrel % 32;
        int k0 = kc * 32;
        int n0 = ntg * 64;               // 64-col segment, entirely within Wa (n<256) or Wb
#pragma unroll
        for (int pass = 0; pass < 8; pass++) {
            int kl = pass * 4 + (t >> 6);
            int k = k0 + kl;
            int n = n0 + (t & 63);
            float v = (n < 256) ? fc1_w[(size_t)k * 256 + n]
                                : fc1_w[(size_t)(CC + k) * 256 + (n - 256)];
            sw[kl][t & 63] = v;
        }
        __syncthreads();
        int local_nt = t >> 6;
        int lane = t & 63;
        int nn = lane & 15;
        int q = lane >> 4;
        int nl = local_nt * 16 + nn;
        unsigned short vh[8], vl[8];
#pragma unroll
        for (int j = 0; j < 8; j++) {
            float v = sw[q * 8 + j][nl];
            unsigned short h = f2bf(v);
            vh[j] = h;
            vl[j] = f2bf(v - bf2f(h));
        }
        uint4 ph, pl;
        ph.x = (unsigned)vh[0] | ((unsigned)vh[1] << 16);
        ph.y = (unsigned)vh[2] | ((unsigned)vh[3] << 16);
        ph.z = (unsigned)vh[4] | ((unsigned)vh[5] << 16);
        ph.w = (unsigned)vh[6] | ((unsigned)vh[7] << 16);
        pl.x = (unsigned)vl[0] | ((unsigned)vl[1] << 16);
        pl.y = (unsigned)vl[2] | ((unsigned)vl[3] << 16);
        pl.z = (unsigned)vl[4] | ((unsigned)vl[5] << 16);
        pl.w = (unsigned)vl[6] | ((unsigned)vl[7] << 16);
        int nt = ntg * 4 + local_nt;
        size_t o = (size_t)nt * 32 * 64 + kc * 64 + lane;
        Bh[o] = ph; Bl[o] = pl;
    } else {                            // ---- pack wg rows into float4 per c ----
        int c = t;
        float4 w;
        w.x = fc1_w[(size_t)(2 * CC + 0) * HR + c];
        w.y = fc1_w[(size_t)(2 * CC + 1) * HR + c];
        w.z = fc1_w[(size_t)(2 * CC + 2) * HR + c];
        w.w = fc1_w[(size_t)(2 * CC + 3) * HR + c];
        wgp[c] = w;
    }
}

// ---------------- LDS-staged MFMA GEMM: [0,48) p12 (128x64 tiles) | [48,96) xw1 (128x128 tiles) ----------------
// 512 thr / 8 waves. Wave w owns mt = bm*8+w (full K accumulation, no cross-wave reduce).
// Double-buffered K-chunks (1 kc = 32 K per chunk); register-staged async prefetch of kc+1.
__global__ __launch_bounds__(512) void k_mm2(const uint4* __restrict__ Ah,
        const uint4* __restrict__ Al, const uint4* __restrict__ Bh,
        const uint4* __restrict__ Bl, const float* __restrict__ fc1_b,
        float* __restrict__ p1, float* __restrict__ p2t,
        const uint4* __restrict__ Asw, const uint4* __restrict__ Bsw,
        float* __restrict__ xw1) {
    __shared__ uint4 lbuf[2][1536];     // p12: 24 rows/buf (16 A h/l + 8 B h/l); xw1: 16 rows/buf
    int t = threadIdx.x;
    int w = t >> 6, lane = t & 63;
    int blk0 = blockIdx.x;
    if (blk0 < 48) {
        // ---- p12 split-bf16: rows mt=bm*8..+8, cols nt=bn*4..+4 (64 cols) ----
        int bm = blk0 >> 3, bn = blk0 & 7;
        f32x4 acc[4];
#pragma unroll
        for (int j = 0; j < 4; j++) acc[j] = (f32x4){0.f, 0.f, 0.f, 0.f};
        // staging: 24 rows of 1KB per chunk; wave w stages rows w*3..w*3+2
        const uint4* sb[3];
        int ldsrow[3];
#pragma unroll
        for (int q = 0; q < 3; q++) {
            int r = w * 3 + q;
            ldsrow[q] = r * 64 + lane;
            if (r < 16) {               // A rows: mtl=r>>1, hl=r&1
                int mtl = r >> 1, hl = r & 1;
                sb[q] = (hl ? Al : Ah) + (size_t)(bm * 8 + mtl) * 32 * 64 + lane;
            } else {                    // B rows: ntl=(r-16)>>1, hl
                int rb = r - 16;
                int ntl = rb >> 1, hl = rb & 1;
                sb[q] = (hl ? Bl : Bh) + (size_t)(bn * 4 + ntl) * 32 * 64 + lane;
            }
        }
        uint4 regs[3];
#pragma unroll
        for (int q = 0; q < 3; q++) regs[q] = sb[q][0];
#pragma unroll
        for (int q = 0; q < 3; q++) lbuf[0][ldsrow[q]] = regs[q];
        __syncthreads();
        for (int kc = 0; kc < 32; kc++) {
            const uint4* lb = lbuf[kc & 1];
            if (kc < 31) {
#pragma unroll
                for (int q = 0; q < 3; q++) regs[q] = sb[q][(kc + 1) * 64];
            }
            uint4 a_h = lb[(2 * w) * 64 + lane];
            uint4 a_l = lb[(2 * w + 1) * 64 + lane];
#pragma unroll
            for (int ntl = 0; ntl < 4; ntl++) {
                uint4 b_h = lb[(16 + 2 * ntl) * 64 + lane];
                uint4 b_l = lb[(16 + 2 * ntl + 1) * 64 + lane];
                acc[ntl] = __builtin_amdgcn_mfma_f32_16x16x32_bf16(*(bf16x8*)&a_h, *(bf16x8*)&b_h, acc[ntl], 0, 0, 0);
                acc[ntl] = __builtin_amdgcn_mfma_f32_16x16x32_bf16(*(bf16x8*)&a_h, *(bf16x8*)&b_l, acc[ntl], 0, 0, 0);
                acc[ntl] = __builtin_amdgcn_mfma_f32_16x16x32_bf16(*(bf16x8*)&a_l, *(bf16x8*)&b_h, acc[ntl], 0, 0, 0);
            }
            __syncthreads();
            if (kc < 31) {
#pragma unroll
                for (int q = 0; q < 3; q++) lbuf[(kc & 1) ^ 1][ldsrow[q]] = regs[q];
                __syncthreads();
            }
        }
        int colb = lane & 15;
        int rbase = (lane >> 4) * 4;
        int mt = bm * 8 + w;
#pragma unroll
        for (int ntl = 0; ntl < 4; ntl++) {
            int col = (bn * 4 + ntl) * 16 + colb;
            if (col < 256) {
                float bias = fc1_b[col];
#pragma unroll
                for (int r = 0; r < 4; r++) {
                    int rr = mt * 16 + rbase + r;
                    p1[(size_t)rr * 256 + col] = acc[ntl][r] + bias;
                }
            } else {
#pragma unroll
                for (int r = 0; r < 4; r++) {
                    int rr = mt * 16 + rbase + r;
                    p2t[((size_t)(rr / NN) * 256 + (col - 256)) * NN + (rr % NN)] = acc[ntl][r];
                }
            }
        }
    } else {
        // ---- xw1 bf16: rows mt=bm*8..+8, cols nt=bn*8..+8 (128 cols), K=33 kc ----
        int blk = blk0 - 48;
        int bm = blk >> 3, bn = blk & 7;
        f32x4 acc[8];
#pragma unroll
        for (int j = 0; j < 8; j++) acc[j] = (f32x4){0.f, 0.f, 0.f, 0.f};
        // staging: 16 rows per chunk; wave w stages rows w*2, w*2+1
        const uint4* sb[2];
        int ldsrow[2];
#pragma unroll
        for (int q = 0; q < 2; q++) {
            int r = w * 2 + q;
            ldsrow[q] = r * 64 + lane;
            if (r < 8) sb[q] = Asw + (size_t)(bm * 8 + r) * 33 * 64 + lane;
            else       sb[q] = Bsw + (size_t)(bn * 8 + (r - 8)) * 33 * 64 + lane;
        }
        uint4 regs[2];
#pragma unroll
        for (int q = 0; q < 2; q++) regs[q] = sb[q][0];
#pragma unroll
        for (int q = 0; q < 2; q++) lbuf[0][ldsrow[q]] = regs[q];
        __syncthreads();
        for (int kc = 0; kc < 33; kc++) {
            const uint4* lb = lbuf[kc & 1];
            if (kc < 32) {
#pragma unroll
                for (int q = 0; q < 2; q++) regs[q] = sb[q][(kc + 1) * 64];
            }
            uint4 av = lb[w * 64 + lane];
#pragma unroll
            for (int ntl = 0; ntl < 8; ntl++) {
                uint4 bv = lb[(8 + ntl) * 64 + lane];
                acc[ntl] = __builtin_amdgcn_mfma_f32_16x16x32_bf16(*(bf16x8*)&av, *(bf16x8*)&bv, acc[ntl], 0, 0, 0);
            }
            __syncthreads();
            if (kc < 32) {
#pragma unroll
                for (int q = 0; q < 2; q++) lbuf[(kc & 1) ^ 1][ldsrow[q]] = regs[q];
                __syncthreads();
            }
        }
        int colb = lane & 15;
        int rbase = (lane >> 4) * 4;
        int mt = bm * 8 + w;
#pragma unroll
        for (int ntl = 0; ntl < 8; ntl++) {
            int col = (bn * 8 + ntl) * 16 + colb;
#pragma unroll
            for (int r = 0; r < 4; r++) {
                int rr = mt * 16 + rbase + r;
                xw1[(size_t)rr * 1024 + col] = acc[ntl][r];
            }
        }
    }
}

// ---------------- merged: [0,768) rel quarter-blocks (4 rows x 64 ch) | [768,1536) att1 dots ----------------
__global__ __launch_bounds__(384) void k_relatt(const float* __restrict__ p1,
        const float* __restrict__ p2t, const float* __restrict__ boxes,
        const float4* __restrict__ wgp, const float* __restrict__ fc2_w,
        float* __restrict__ relq,
        const float* __restrict__ xw1, const float* __restrict__ att_src,
        const float* __restrict__ att_dst, float* __restrict__ a_s,
        float* __restrict__ a_d) {
    int blk0 = blockIdx.x;
    if (blk0 < 768) {
        int b = blk0 / 384;
        int rem = blk0 - b * 384;
        int q = rem & 3;              // channel quarter
        int rg = rem >> 2;            // row group 0..95
        int i0 = rg * 4;
        int row0 = b * NN + i0;
        int j = threadIdx.x;
        float4 br0 = *(const float4*)(boxes + (size_t)row0 * 4);
        float4 br1 = *(const float4*)(boxes + (size_t)(row0 + 1) * 4);
        float4 br2 = *(const float4*)(boxes + (size_t)(row0 + 2) * 4);
        float4 br3 = *(const float4*)(boxes + (size_t)(row0 + 3) * 4);
        float4 bj = *(const float4*)(boxes + ((size_t)b * NN + j) * 4);
        float g00 = fabsf(br0.x - bj.x), g01 = fabsf(br0.y - bj.y);
        float g02 = fabsf(br0.z - bj.z), g03 = fabsf(br0.w - bj.w);
        float g10 = fabsf(br1.x - bj.x), g11 = fabsf(br1.y - bj.y);
        float g12 = fabsf(br1.z - bj.z), g13 = fabsf(br1.w - bj.w);
        float g20 = fabsf(br2.x - bj.x), g21 = fabsf(br2.y - bj.y);
        float g22 = fabsf(br2.z - bj.z), g23 = fabsf(br2.w - bj.w);
        float g30 = fabsf(br3.x - bj.x), g31 = fabsf(br3.y - bj.y);
        float g32 = fabsf(br3.z - bj.z), g33 = fabsf(br3.w - bj.w);
        const float* p1b = p1 + (size_t)row0 * HR + q * 64;   // rows stride HR
        const float* p2b = p2t + (size_t)b * HR * NN + (size_t)(q * 64) * NN + j;
        const float4* wg = wgp + q * 64;
        const float* w2 = fc2_w + q * 64;
        float acc0 = 0.f, acc1 = 0.f, acc2 = 0.f, acc3 = 0.f;
#pragma unroll 4
        for (int c = 0; c < 64; c++) {
            float4 w = wg[c];             // wave-uniform -> s_load_dwordx4
            float wc = w2[c];
            float pa0 = p1b[c];           // wave-uniform
            float pa1 = p1b[c + HR];
            float pa2 = p1b[c + 2 * HR];
            float pa3 = p1b[c + 3 * HR];
            float p2v = p2b[(size_t)c * NN];   // per-lane, coalesced
            float v0 = pa0 + p2v + g00 * w.x + g01 * w.y + g02 * w.z + g03 * w.w;
            float v1 = pa1 + p2v + g10 * w.x + g11 * w.y + g12 * w.z + g13 * w.w;
            float v2 = pa2 + p2v + g20 * w.x + g21 * w.y + g22 * w.z + g23 * w.w;
            float v3 = pa3 + p2v + g30 * w.x + g31 * w.y + g32 * w.z + g33 * w.w;
            acc0 += fmaxf(v0, 0.f) * wc;
            acc1 += fmaxf(v1, 0.f) * wc;
            acc2 += fmaxf(v2, 0.f) * wc;
            acc3 += fmaxf(v3, 0.f) * wc;
        }
        float* dst = relq + ((size_t)q * (BB * NN) + row0) * NN + j;
        dst[0]          = acc0;
        dst[NN]         = acc1;
        dst[2 * NN]     = acc2;
        dst[3 * (size_t)NN] = acc3;
    } else {
        int node = blk0 - 768;
        int t = threadIdx.x;
        if (t >= 256) return;
        int w = t >> 6;
        int lane = t & 63;
        const float4* xr = (const float4*)(xw1 + (size_t)node * 1024 + w * 256);
        const float4* sr = (const float4*)(att_src + w * 256);
        const float4* dr = (const float4*)(att_dst + w * 256);
        float4 x = xr[lane];
        float4 s = sr[lane];
        float4 d = dr[lane];
        float ps = x.x * s.x + x.y * s.y + x.z * s.z + x.w * s.w;
        float pd = x.x * d.x + x.y * d.y + x.z * d.z + x.w * d.w;
#pragma unroll
        for (int off = 32; off > 0; off >>= 1) {
            ps += __shfl_xor(ps, off);
            pd += __shfl_xor(pd, off);
        }
        if (lane == 0) {
            a_s[(size_t)node * NHEADS + w] = ps;
            a_d[(size_t)node * NHEADS + w] = pd;
        }
    }
}

// ---------------- top-8 per row + edge scatter (sums 4 quarter-partials, masks diag) ----------------
__global__ __launch_bounds__(64) void k_topk_inv(const float* __restrict__ relq,
        int* __restrict__ counts, int* __restrict__ inlist) {
    int row = blockIdx.x;            // b*N+i
    int b = row / NN;
    int i = row - b * NN;
    int t = threadIdx.x;
    const float* r0 = relq + (size_t)row * NN;
    const float* r1 = r0 + (size_t)(BB * NN) * NN;
    const float* r2 = r1 + (size_t)(BB * NN) * NN;
    const float* r3 = r2 + (size_t)(BB * NN) * NN;
    float v[6]; int id[6];
#pragma unroll
    for (int q = 0; q < 6; q++) {
        int j = t + q * 64;
        float val = ((r0[j] + r1[j]) + r2[j]) + r3[j];
        if (j == i) val = -INFINITY;   // diag mask (== reference's -1e6)
        v[q] = val; id[q] = j;
    }
    int mine = -1;
    for (int k = 0; k < TOPK; k++) {
        float bv = -INFINITY; int bi = NN;
#pragma unroll
        for (int q = 0; q < 6; q++) {
            if (v[q] > bv || (v[q] == bv && id[q] < bi)) { bv = v[q]; bi = id[q]; }
        }
        for (int off = 32; off > 0; off >>= 1) {
            float ov = __shfl_down(bv, off);
            int   oi = __shfl_down(bi, off);
            if (ov > bv || (ov == bv && oi < bi)) { bv = ov; bi = oi; }
        }
        bi = __shfl(bi, 0);
        if (t == k) mine = bi;
#pragma unroll
        for (int q = 0; q < 6; q++) if (id[q] == bi) v[q] = -INFINITY;
    }
    if (t < TOPK) {
        int tg = b * NN + mine;
        int q = atomicAdd(&counts[tg], 1);
        inlist[(size_t)tg * CAP + q] = i;
    } else if (t == TOPK) {          // self loop
        int q = atomicAdd(&counts[row], 1);
        inlist[(size_t)row * CAP + q] = i;
    }
}

// ---------------- GAT1 aggregation: ONE block per node (512 thr), all 4 heads, no atomics ----------------
__global__ __launch_bounds__(512) void k_agg1(const int* __restrict__ counts,
        const int* __restrict__ inlist, const float* __restrict__ a_s,
        const float* __restrict__ a_d, const float* __restrict__ xw1,
        const float* __restrict__ gat1_b, const float* __restrict__ w2,
        float* __restrict__ xw2) {
    __shared__ int slist[CAP];
    __shared__ float walpha[NHEADS][CAP];
    __shared__ float redp[16];
    int node = blockIdx.x;
    int b = node / NN;
    int t = threadIdx.x;
    int wid = t >> 6;
    int lane = t & 63;
    int deg = counts[node];
    for (int e = t; e < deg; e += 512) slist[e] = inlist[(size_t)node * CAP + e];
    __syncthreads();
    if (t < 256) {                   // waves 0..3: softmax for head = wid (same FP order as before)
        int h = wid;
        float ad = a_d[(size_t)node * NHEADS + h];
        float vals[7];
        int cnt = 0;
        float vmax = -INFINITY;
        for (int e = lane; e < deg; e += 64) {
            float x = a_s[(size_t)(b * NN + slist[e]) * NHEADS + h] + ad;
            x = x >= 0.f ? x : NEG * x;
            vals[cnt++] = x;
            vmax = fmaxf(vmax, x);
        }
#pragma unroll
        for (int off = 32; off > 0; off >>= 1)
            vmax = fmaxf(vmax, __shfl_xor(vmax, off));
        float sum = 0.f;
        for (int i = 0; i < cnt; i++) {
            vals[i] = expf(vals[i] - vmax);
            sum += vals[i];
        }
#pragma unroll
        for (int off = 32; off > 0; off >>= 1)
            sum += __shfl_xor(sum, off);
        float inv = 1.f / fmaxf(sum, 1e-16f);
        cnt = 0;
        for (int e = lane; e < deg; e += 64) walpha[h][e] = vals[cnt++] * inv;
    }
    __syncthreads();
    // gather: thread t handles d0 = t (heads 0/1), d1 = t+512 (heads 2/3)
    int d0 = t, d1 = t + 512;
    int h0 = d0 >> 8, h1 = d1 >> 8;
    float acc0 = 0.f, acc1 = 0.f;
    for (int e = 0; e < deg; e++) {
        const float* xr = xw1 + (size_t)(b * NN + slist[e]) * 1024;
        acc0 += walpha[h0][e] * xr[d0];
        acc1 += walpha[h1][e] * xr[d1];
    }
    float o0 = fmaxf(acc0 + gat1_b[d0], 0.f);
    float o1 = fmaxf(acc1 + gat1_b[d1], 0.f);
    float p0 = o0 * w2[d0 * 2]     + o1 * w2[d1 * 2];
    float p1v = o0 * w2[d0 * 2 + 1] + o1 * w2[d1 * 2 + 1];
#pragma unroll
    for (int off = 32; off > 0; off >>= 1) {
        p0 += __shfl_xor(p0, off);
        p1v += __shfl_xor(p1v, off);
    }
    if (lane == 0) { redp[wid] = p0; redp[8 + wid] = p1v; }
    __syncthreads();
    if (t == 0) {
        float s0 = 0.f, s1 = 0.f;
#pragma unroll
        for (int q = 0; q < 8; q++) { s0 += redp[q]; s1 += redp[8 + q]; }
        xw2[(size_t)node * 2]     = s0;
        xw2[(size_t)node * 2 + 1] = s1;
    }
}

// ---------------- GAT2 aggregation -> output (one wave per node; on-the-fly att dots) ----------------
__global__ __launch_bounds__(64) void k_agg2(const int* __restrict__ counts,
        const int* __restrict__ inlist, const float* __restrict__ xw2,
        const float* __restrict__ as2, const float* __restrict__ ad2,
        const float* __restrict__ b2, float* __restrict__ out) {
    int node = blockIdx.x;
    int b = node / NN;
    int lane = threadIdx.x;
    int deg = counts[node];
    float s0 = as2[0], s1 = as2[1];
    float d0 = ad2[0], d1 = ad2[1];
    float2 xwn = *(const float2*)(xw2 + (size_t)node * 2);
    float ad = xwn.x * d0 + xwn.y * d1;
    float vals[7], xs0[7], xs1[7];
    int cnt = 0;
    float vmax = -INFINITY;
    for (int e = lane; e < deg; e += 64) {
        int s = b * NN + inlist[(size_t)node * CAP + e];
        float2 xws = *(const float2*)(xw2 + (size_t)s * 2);
        float x = xws.x * s0 + xws.y * s1 + ad;
        x = x >= 0.f ? x : NEG * x;
        xs0[cnt] = xws.x; xs1[cnt] = xws.y; vals[cnt] = x; cnt++;
        vmax = fmaxf(vmax, x);
    }
#pragma unroll
    for (int off = 32; off > 0; off >>= 1)
        vmax = fmaxf(vmax, __shfl_xor(vmax, off));
    float sum = 0.f;
    for (int i = 0; i < cnt; i++) {
        vals[i] = expf(vals[i] - vmax);
        sum += vals[i];
    }
#pragma unroll
    for (int off = 32; off > 0; off >>= 1)
        sum += __shfl_xor(sum, off);
    float inv = 1.f / fmaxf(sum, 1e-16f);
    float a0 = 0.f, a1 = 0.f;
    for (int i = 0; i < cnt; i++) {
        a0 += vals[i] * xs0[i];
        a1 += vals[i] * xs1[i];
    }
#pragma unroll
    for (int off = 32; off > 0; off >>= 1) {
        a0 += __shfl_xor(a0, off);
        a1 += __shfl_xor(a1, off);
    }
    if (lane == 0) {
        out[(size_t)node * 2]     = a0 * inv + b2[0];
        out[(size_t)node * 2 + 1] = a1 * inv + b2[1];
    }
}

extern "C" void kernel_launch(void* const* d_in, const int* in_sizes, int n_in,
                              void* d_out, int out_size, void* d_ws, size_t ws_size,
                              hipStream_t stream) {
    const float* feats  = (const float*)d_in[0];
    const float* boxes  = (const float*)d_in[1];
    const float* fc1_w  = (const float*)d_in[2];
    const float* fc1_b  = (const float*)d_in[3];
    const float* fc2_w  = (const float*)d_in[4];
    const float* fc2_b  = (const float*)d_in[5];
    const float* gat1_w = (const float*)d_in[6];
    const float* g1as   = (const float*)d_in[7];
    const float* g1ad   = (const float*)d_in[8];
    const float* gat1_b = (const float*)d_in[9];
    const float* gat2_w = (const float*)d_in[10];
    const float* g2as   = (const float*)d_in[11];
    const float* g2ad   = (const float*)d_in[12];
    const float* gat2_b = (const float*)d_in[13];
    float* out = (float*)d_out;
    (void)fc2_b;   // constant offset: order-irrelevant for top-k; GAT consumes edges only

    char* ws = (char*)d_ws;
    size_t off = 0;
    auto alloc = [&](size_t bytes) -> void* {
        void* p = ws + off;
        off += (bytes + 255) / 256 * 256;
        return p;
    };
    int*   counts = (int*)alloc((size_t)BB * NN * 4);
    int*   inlist = (int*)alloc((size_t)BB * NN * CAP * 4);
    float* p1     = (float*)alloc((size_t)BB * NN * HR * 4);
    float* p2t    = (float*)alloc((size_t)BB * HR * NN * 4);
    float* relq   = (float*)alloc((size_t)4 * BB * NN * NN * 4);
    float* xw1    = (float*)alloc((size_t)BB * NN * 1024 * 4);
    float* a_s1   = (float*)alloc((size_t)BB * NN * NHEADS * 4);
    float* a_d1   = (float*)alloc((size_t)BB * NN * NHEADS * 4);
    float* xw2    = (float*)alloc((size_t)BB * NN * 2 * 4);
    uint4* Asw    = (uint4*)alloc((size_t)48 * 33 * 64 * 16);
    uint4* Bsw    = (uint4*)alloc((size_t)64 * 33 * 64 * 16);
    uint4* Ah     = (uint4*)alloc((size_t)48 * 32 * 64 * 16);
    uint4* Al     = (uint4*)alloc((size_t)48 * 32 * 64 * 16);
    uint4* Bh     = (uint4*)alloc((size_t)32 * 32 * 64 * 16);
    uint4* Bl     = (uint4*)alloc((size_t)32 * 32 * 64 * 16);
    float4* wgp   = (float4*)alloc((size_t)HR * 16);
    (void)ws_size; (void)in_sizes; (void)n_in; (void)out_size;

    k_prep<<<1565, 256, 0, stream>>>(feats, boxes, gat1_w, fc1_w,
                                     Asw, Bsw, Ah, Al, Bh, Bl, wgp, counts);
    k_mm2<<<96, 512, 0, stream>>>(Ah, Al, Bh, Bl, fc1_b, p1, p2t, Asw, Bsw, xw1);
    k_relatt<<<1536, 384, 0, stream>>>(p1, p2t, boxes, wgp, fc2_w, relq,
                                       xw1, g1as, g1ad, a_s1, a_d1);
    k_topk_inv<<<BB * NN, 64, 0, stream>>>(relq, counts, inlist);
    k_agg1<<<BB * NN, 512, 0, stream>>>(counts, inlist, a_s1, a_d1, xw1,
                                        gat1_b, gat2_w, xw2);
    k_agg2<<<BB * NN, 64, 0, stream>>>(counts, inlist, xw2, g2as, g2ad, gat2_b, out);
}

// Round 6
// 158.844 us; speedup vs baseline: 1.3183x; 1.3183x over previous
//
#include <hip/hip_runtime.h>

#define BB 2
#define NN 384
#define CC 1024
#define HR 256      // H_REPN
#define NHEADS 4
#define TOPK 8
#define CAP 448
#define NEG 0.2f

typedef __attribute__((ext_vector_type(8))) short bf16x8;
typedef __attribute__((ext_vector_type(4))) float f32x4;

__device__ __forceinline__ unsigned short f2bf(float v) {
    unsigned u = __float_as_uint(v);
    return (unsigned short)((u + 0x7FFFu + ((u >> 16) & 1u)) >> 16);
}
__device__ __forceinline__ float bf2f(unsigned short h) {
    return __uint_as_float((unsigned)h << 16);
}

// ---------------- merged prep: Asw, Bsw, Ah/Al, Bh/Bl, wgp, zero counts ----------------
// block ranges: [0,396) prepa | [396,924) prepb-tiled | [924,1308) prepa2 | [1308,1564) prepb2-tiled | 1564 wgp
__global__ __launch_bounds__(256) void k_prep(const float* __restrict__ feats,
        const float* __restrict__ boxes, const float* __restrict__ gat1_w,
        const float* __restrict__ fc1_w,
        uint4* __restrict__ Asw, uint4* __restrict__ Bsw,
        uint4* __restrict__ Ah, uint4* __restrict__ Al,
        uint4* __restrict__ Bh, uint4* __restrict__ Bl,
        float4* __restrict__ wgp, int* __restrict__ counts) {
    __shared__ float sw[32][65];
    int blk = blockIdx.x;
    int t = threadIdx.x;
    int gflat = blk * 256 + t;
    if (gflat < BB * NN) counts[gflat] = 0;

    if (blk < 396) {                    // ---- prep A for xw1 (Kp=1056), float4 loads ----
        int flat = gflat;
        int lane = flat & 63;
        int kc = (flat >> 6) % 33;
        int mt = flat / (33 * 64);
        int m = mt * 16 + (lane & 15);
        int k0 = kc * 32 + (lane >> 4) * 8;
        unsigned short vals[8];
        const float s = 1.0f / 800.0f;
        if (kc < 32) {                   // all k < CC: branchless vector loads
            const float4* src = (const float4*)(feats + (size_t)m * CC + k0);
            float4 v0 = src[0], v1 = src[1];
            vals[0] = f2bf(v0.x); vals[1] = f2bf(v0.y);
            vals[2] = f2bf(v0.z); vals[3] = f2bf(v0.w);
            vals[4] = f2bf(v1.x); vals[5] = f2bf(v1.y);
            vals[6] = f2bf(v1.z); vals[7] = f2bf(v1.w);
        } else {                         // tail: geom4 + zero pad
#pragma unroll
            for (int j = 0; j < 8; j++) {
                int k = k0 + j;
                float v;
                if (k < CC) v = feats[(size_t)m * CC + k];
                else if (k < CC + 4) {
                    const float* bx = boxes + (size_t)m * 4;
                    int gk = k - CC;
                    v = (gk == 0) ? bx[0] * s : (gk == 1) ? bx[1] * s
                      : (gk == 2) ? (bx[2] - bx[0]) * s : (bx[3] - bx[1]) * s;
                } else v = 0.f;
                vals[j] = f2bf(v);
            }
        }
        uint4 pk;
        pk.x = (unsigned)vals[0] | ((unsigned)vals[1] << 16);
        pk.y = (unsigned)vals[2] | ((unsigned)vals[3] << 16);
        pk.z = (unsigned)vals[4] | ((unsigned)vals[5] << 16);
        pk.w = (unsigned)vals[6] | ((unsigned)vals[7] << 16);
        Asw[flat] = pk;
    } else if (blk < 924) {             // ---- prep B for xw1 (gat1_w) via LDS tile, coalesced ----
        int blkrel = blk - 396;          // ntg*33 + kc ; ntg in [0,16), kc in [0,33)
        int ntg = blkrel / 33;
        int kc  = blkrel % 33;
        int k0 = kc * 32;
        int n0 = ntg * 64;
        // load 32 x 64 tile coalesced (4 rows per pass)
#pragma unroll
        for (int pass = 0; pass < 8; pass++) {
            int kl = pass * 4 + (t >> 6);
            int k = k0 + kl;
            int nl = t & 63;
            float v = (k < CC + 4) ? gat1_w[(size_t)k * 1024 + n0 + nl] : 0.f;
            sw[kl][nl] = v;
        }
        __syncthreads();
        int local_nt = t >> 6;           // 0..3
        int lane = t & 63;
        int nn = lane & 15;
        int q = lane >> 4;
        int nl = local_nt * 16 + nn;
        unsigned short vals[8];
#pragma unroll
        for (int j = 0; j < 8; j++) vals[j] = f2bf(sw[q * 8 + j][nl]);
        uint4 pk;
        pk.x = (unsigned)vals[0] | ((unsigned)vals[1] << 16);
        pk.y = (unsigned)vals[2] | ((unsigned)vals[3] << 16);
        pk.z = (unsigned)vals[4] | ((unsigned)vals[5] << 16);
        pk.w = (unsigned)vals[6] | ((unsigned)vals[7] << 16);
        int nt = ntg * 4 + local_nt;
        Bsw[(size_t)nt * 33 * 64 + kc * 64 + lane] = pk;
    } else if (blk < 1308) {            // ---- prep A hi/lo for p12 (feats), float4 loads ----
        int flat = gflat - 924 * 256;
        int lane = flat & 63;
        int kc = (flat >> 6) % 32;
        int mt = flat / (32 * 64);
        int m = mt * 16 + (lane & 15);
        int k0 = kc * 32 + (lane >> 4) * 8;   // always < CC-7
        unsigned short vh[8], vl[8];
        const float4* src = (const float4*)(feats + (size_t)m * CC + k0);
        float4 v0 = src[0], v1 = src[1];
        float vv[8] = {v0.x, v0.y, v0.z, v0.w, v1.x, v1.y, v1.z, v1.w};
#pragma unroll
        for (int j = 0; j < 8; j++) {
            float v = vv[j];
            unsigned short h = f2bf(v);
            vh[j] = h;
            vl[j] = f2bf(v - bf2f(h));
        }
        uint4 ph, pl;
        ph.x = (unsigned)vh[0] | ((unsigned)vh[1] << 16);
        ph.y = (unsigned)vh[2] | ((unsigned)vh[3] << 16);
        ph.z = (unsigned)vh[4] | ((unsigned)vh[5] << 16);
        ph.w = (unsigned)vh[6] | ((unsigned)vh[7] << 16);
        pl.x = (unsigned)vl[0] | ((unsigned)vl[1] << 16);
        pl.y = (unsigned)vl[2] | ((unsigned)vl[3] << 16);
        pl.z = (unsigned)vl[4] | ((unsigned)vl[5] << 16);
        pl.w = (unsigned)vl[6] | ((unsigned)vl[7] << 16);
        Ah[flat] = ph; Al[flat] = pl;
    } else if (blk < 1564) {            // ---- prep B hi/lo for p12 ([Wa|Wb]) via LDS tile ----
        int blkrel = blk - 1308;         // ntg*32 + kc ; ntg in [0,8), kc in [0,32)
        int ntg = blkrel / 32;
        int kc  = blkrel % 32;
        int k0 = kc * 32;
        int n0 = ntg * 64;               // 64-col segment, entirely within Wa (n<256) or Wb
#pragma unroll
        for (int pass = 0; pass < 8; pass++) {
            int kl = pass * 4 + (t >> 6);
            int k = k0 + kl;
            int n = n0 + (t & 63);
            float v = (n < 256) ? fc1_w[(size_t)k * 256 + n]
                                : fc1_w[(size_t)(CC + k) * 256 + (n - 256)];
            sw[kl][t & 63] = v;
        }
        __syncthreads();
        int local_nt = t >> 6;
        int lane = t & 63;
        int nn = lane & 15;
        int q = lane >> 4;
        int nl = local_nt * 16 + nn;
        unsigned short vh[8], vl[8];
#pragma unroll
        for (int j = 0; j < 8; j++) {
            float v = sw[q * 8 + j][nl];
            unsigned short h = f2bf(v);
            vh[j] = h;
            vl[j] = f2bf(v - bf2f(h));
        }
        uint4 ph, pl;
        ph.x = (unsigned)vh[0] | ((unsigned)vh[1] << 16);
        ph.y = (unsigned)vh[2] | ((unsigned)vh[3] << 16);
        ph.z = (unsigned)vh[4] | ((unsigned)vh[5] << 16);
        ph.w = (unsigned)vh[6] | ((unsigned)vh[7] << 16);
        pl.x = (unsigned)vl[0] | ((unsigned)vl[1] << 16);
        pl.y = (unsigned)vl[2] | ((unsigned)vl[3] << 16);
        pl.z = (unsigned)vl[4] | ((unsigned)vl[5] << 16);
        pl.w = (unsigned)vl[6] | ((unsigned)vl[7] << 16);
        int nt = ntg * 4 + local_nt;
        size_t o = (size_t)nt * 32 * 64 + kc * 64 + lane;
        Bh[o] = ph; Bl[o] = pl;
    } else {                            // ---- pack wg rows into float4 per c ----
        int c = t;
        float4 w;
        w.x = fc1_w[(size_t)(2 * CC + 0) * HR + c];
        w.y = fc1_w[(size_t)(2 * CC + 1) * HR + c];
        w.z = fc1_w[(size_t)(2 * CC + 2) * HR + c];
        w.w = fc1_w[(size_t)(2 * CC + 3) * HR + c];
        wgp[c] = w;
    }
}

// ---------------- merged MFMA, 2 m-tiles per block: [0,192) p12 | [192,576) xw1 ----------------
__global__ __launch_bounds__(512) void k_mm(const uint4* __restrict__ Ah,
        const uint4* __restrict__ Al, const uint4* __restrict__ Bh,
        const uint4* __restrict__ Bl, const float* __restrict__ fc1_b,
        float* __restrict__ p1, float* __restrict__ p2t,
        const uint4* __restrict__ Asw, const uint4* __restrict__ Bsw,
        float* __restrict__ xw1) {
    __shared__ float lds[4][64][8];
    int t = threadIdx.x;
    int w = t >> 6;
    int lane = t & 63;
    int g = w & 3;                   // nt sub-group
    int kh = w >> 2;                 // K half
    int blk0 = blockIdx.x;
    if (blk0 < 192) {
        // ---- p1/p2 split-bf16 MFMA, 2 mt per block, K split 2x16 ----
        int mtp = blk0 >> 3;         // 0..23
        int nt = (blk0 & 7) * 4 + g;
        int mt0 = mtp * 2;
        f32x4 acc0 = {0.f, 0.f, 0.f, 0.f};
        f32x4 acc1 = {0.f, 0.f, 0.f, 0.f};
        const uint4* pah0 = Ah + (size_t)mt0 * 32 * 64 + (size_t)kh * 16 * 64 + lane;
        const uint4* pal0 = Al + (size_t)mt0 * 32 * 64 + (size_t)kh * 16 * 64 + lane;
        const uint4* pbh = Bh + (size_t)nt * 32 * 64 + (size_t)kh * 16 * 64 + lane;
        const uint4* pbl = Bl + (size_t)nt * 32 * 64 + (size_t)kh * 16 * 64 + lane;
#pragma unroll 2
        for (int kc = 0; kc < 16; kc++) {
            uint4 ah0 = pah0[kc * 64];
            uint4 al0 = pal0[kc * 64];
            uint4 ah1 = pah0[kc * 64 + 2048];
            uint4 al1 = pal0[kc * 64 + 2048];
            uint4 bh = pbh[kc * 64];
            uint4 bl = pbl[kc * 64];
            acc0 = __builtin_amdgcn_mfma_f32_16x16x32_bf16(*(bf16x8*)&ah0, *(bf16x8*)&bh, acc0, 0, 0, 0);
            acc0 = __builtin_amdgcn_mfma_f32_16x16x32_bf16(*(bf16x8*)&ah0, *(bf16x8*)&bl, acc0, 0, 0, 0);
            acc0 = __builtin_amdgcn_mfma_f32_16x16x32_bf16(*(bf16x8*)&al0, *(bf16x8*)&bh, acc0, 0, 0, 0);
            acc1 = __builtin_amdgcn_mfma_f32_16x16x32_bf16(*(bf16x8*)&ah1, *(bf16x8*)&bh, acc1, 0, 0, 0);
            acc1 = __builtin_amdgcn_mfma_f32_16x16x32_bf16(*(bf16x8*)&ah1, *(bf16x8*)&bl, acc1, 0, 0, 0);
            acc1 = __builtin_amdgcn_mfma_f32_16x16x32_bf16(*(bf16x8*)&al1, *(bf16x8*)&bh, acc1, 0, 0, 0);
        }
        if (kh == 1) {
#pragma unroll
            for (int r = 0; r < 4; r++) { lds[g][lane][r] = acc0[r]; lds[g][lane][4 + r] = acc1[r]; }
        }
        __syncthreads();
        if (kh == 0) {
#pragma unroll
            for (int r = 0; r < 4; r++) { acc0[r] += lds[g][lane][r]; acc1[r] += lds[g][lane][4 + r]; }
            int col = nt * 16 + (lane & 15);
            int rbase = (lane >> 4) * 4;
            if (col < 256) {
                float bias = fc1_b[col];
#pragma unroll
                for (int r = 0; r < 4; r++) {
                    p1[(size_t)(mt0 * 16 + rbase + r) * 256 + col] = acc0[r] + bias;
                    p1[(size_t)(mt0 * 16 + 16 + rbase + r) * 256 + col] = acc1[r] + bias;
                }
            } else {
#pragma unroll
                for (int r = 0; r < 4; r++) {
                    int rr0 = mt0 * 16 + rbase + r;
                    int rr1 = rr0 + 16;
                    p2t[((size_t)(rr0 / NN) * 256 + (col - 256)) * NN + (rr0 % NN)] = acc0[r];
                    p2t[((size_t)(rr1 / NN) * 256 + (col - 256)) * NN + (rr1 % NN)] = acc1[r];
                }
            }
        }
    } else {
        // ---- xw1 MFMA bf16, 2 mt per block, K split 17+16 ----
        int blk = blk0 - 192;        // mtp*16 + ntgrp
        int mtp = blk >> 4;
        int nt = (blk & 15) * 4 + g;
        int mt0 = mtp * 2;
        int nk = kh ? 16 : 17;
        f32x4 acc0 = {0.f, 0.f, 0.f, 0.f};
        f32x4 acc1 = {0.f, 0.f, 0.f, 0.f};
        const uint4* pa0 = Asw + (size_t)mt0 * 33 * 64 + (size_t)kh * 17 * 64 + lane;
        const uint4* pb = Bsw + (size_t)nt * 33 * 64 + (size_t)kh * 17 * 64 + lane;
#pragma unroll 4
        for (int kc = 0; kc < nk; kc++) {
            uint4 a0 = pa0[kc * 64];
            uint4 a1 = pa0[kc * 64 + 2112];
            uint4 bv = pb[kc * 64];
            acc0 = __builtin_amdgcn_mfma_f32_16x16x32_bf16(*(bf16x8*)&a0, *(bf16x8*)&bv, acc0, 0, 0, 0);
            acc1 = __builtin_amdgcn_mfma_f32_16x16x32_bf16(*(bf16x8*)&a1, *(bf16x8*)&bv, acc1, 0, 0, 0);
        }
        if (kh == 1) {
#pragma unroll
            for (int r = 0; r < 4; r++) { lds[g][lane][r] = acc0[r]; lds[g][lane][4 + r] = acc1[r]; }
        }
        __syncthreads();
        if (kh == 0) {
#pragma unroll
            for (int r = 0; r < 4; r++) { acc0[r] += lds[g][lane][r]; acc1[r] += lds[g][lane][4 + r]; }
            int col = nt * 16 + (lane & 15);
            int rbase = (lane >> 4) * 4;
#pragma unroll
            for (int r = 0; r < 4; r++) {
                xw1[(size_t)(mt0 * 16 + rbase + r) * 1024 + col] = acc0[r];
                xw1[(size_t)(mt0 * 16 + 16 + rbase + r) * 1024 + col] = acc1[r];
            }
        }
    }
}

// ---------------- merged: [0,768) rel quarter-blocks (4 rows x 64 ch) | [768,1536) att1 dots ----------------
__global__ __launch_bounds__(384) void k_relatt(const float* __restrict__ p1,
        const float* __restrict__ p2t, const float* __restrict__ boxes,
        const float4* __restrict__ wgp, const float* __restrict__ fc2_w,
        float* __restrict__ relq,
        const float* __restrict__ xw1, const float* __restrict__ att_src,
        const float* __restrict__ att_dst, float* __restrict__ a_s,
        float* __restrict__ a_d) {
    int blk0 = blockIdx.x;
    if (blk0 < 768) {
        int b = blk0 / 384;
        int rem = blk0 - b * 384;
        int q = rem & 3;              // channel quarter
        int rg = rem >> 2;            // row group 0..95
        int i0 = rg * 4;
        int row0 = b * NN + i0;
        int j = threadIdx.x;
        float4 br0 = *(const float4*)(boxes + (size_t)row0 * 4);
        float4 br1 = *(const float4*)(boxes + (size_t)(row0 + 1) * 4);
        float4 br2 = *(const float4*)(boxes + (size_t)(row0 + 2) * 4);
        float4 br3 = *(const float4*)(boxes + (size_t)(row0 + 3) * 4);
        float4 bj = *(const float4*)(boxes + ((size_t)b * NN + j) * 4);
        float g00 = fabsf(br0.x - bj.x), g01 = fabsf(br0.y - bj.y);
        float g02 = fabsf(br0.z - bj.z), g03 = fabsf(br0.w - bj.w);
        float g10 = fabsf(br1.x - bj.x), g11 = fabsf(br1.y - bj.y);
        float g12 = fabsf(br1.z - bj.z), g13 = fabsf(br1.w - bj.w);
        float g20 = fabsf(br2.x - bj.x), g21 = fabsf(br2.y - bj.y);
        float g22 = fabsf(br2.z - bj.z), g23 = fabsf(br2.w - bj.w);
        float g30 = fabsf(br3.x - bj.x), g31 = fabsf(br3.y - bj.y);
        float g32 = fabsf(br3.z - bj.z), g33 = fabsf(br3.w - bj.w);
        const float* p1b = p1 + (size_t)row0 * HR + q * 64;   // rows stride HR
        const float* p2b = p2t + (size_t)b * HR * NN + (size_t)(q * 64) * NN + j;
        const float4* wg = wgp + q * 64;
        const float* w2 = fc2_w + q * 64;
        float acc0 = 0.f, acc1 = 0.f, acc2 = 0.f, acc3 = 0.f;
#pragma unroll 4
        for (int c = 0; c < 64; c++) {
            float4 w = wg[c];             // wave-uniform -> s_load_dwordx4
            float wc = w2[c];
            float pa0 = p1b[c];           // wave-uniform
            float pa1 = p1b[c + HR];
            float pa2 = p1b[c + 2 * HR];
            float pa3 = p1b[c + 3 * HR];
            float p2v = p2b[(size_t)c * NN];   // per-lane, coalesced
            float v0 = pa0 + p2v + g00 * w.x + g01 * w.y + g02 * w.z + g03 * w.w;
            float v1 = pa1 + p2v + g10 * w.x + g11 * w.y + g12 * w.z + g13 * w.w;
            float v2 = pa2 + p2v + g20 * w.x + g21 * w.y + g22 * w.z + g23 * w.w;
            float v3 = pa3 + p2v + g30 * w.x + g31 * w.y + g32 * w.z + g33 * w.w;
            acc0 += fmaxf(v0, 0.f) * wc;
            acc1 += fmaxf(v1, 0.f) * wc;
            acc2 += fmaxf(v2, 0.f) * wc;
            acc3 += fmaxf(v3, 0.f) * wc;
        }
        float* dst = relq + ((size_t)q * (BB * NN) + row0) * NN + j;
        dst[0]          = acc0;
        dst[NN]         = acc1;
        dst[2 * NN]     = acc2;
        dst[3 * (size_t)NN] = acc3;
    } else {
        int node = blk0 - 768;
        int t = threadIdx.x;
        if (t >= 256) return;
        int w = t >> 6;
        int lane = t & 63;
        const float4* xr = (const float4*)(xw1 + (size_t)node * 1024 + w * 256);
        const float4* sr = (const float4*)(att_src + w * 256);
        const float4* dr = (const float4*)(att_dst + w * 256);
        float4 x = xr[lane];
        float4 s = sr[lane];
        float4 d = dr[lane];
        float ps = x.x * s.x + x.y * s.y + x.z * s.z + x.w * s.w;
        float pd = x.x * d.x + x.y * d.y + x.z * d.z + x.w * d.w;
#pragma unroll
        for (int off = 32; off > 0; off >>= 1) {
            ps += __shfl_xor(ps, off);
            pd += __shfl_xor(pd, off);
        }
        if (lane == 0) {
            a_s[(size_t)node * NHEADS + w] = ps;
            a_d[(size_t)node * NHEADS + w] = pd;
        }
    }
}

// ---------------- top-8 per row + edge scatter (sums 4 quarter-partials, masks diag) ----------------
__global__ __launch_bounds__(64) void k_topk_inv(const float* __restrict__ relq,
        int* __restrict__ counts, int* __restrict__ inlist) {
    int row = blockIdx.x;            // b*N+i
    int b = row / NN;
    int i = row - b * NN;
    int t = threadIdx.x;
    const float* r0 = relq + (size_t)row * NN;
    const float* r1 = r0 + (size_t)(BB * NN) * NN;
    const float* r2 = r1 + (size_t)(BB * NN) * NN;
    const float* r3 = r2 + (size_t)(BB * NN) * NN;
    float v[6]; int id[6];
#pragma unroll
    for (int q = 0; q < 6; q++) {
        int j = t + q * 64;
        float val = ((r0[j] + r1[j]) + r2[j]) + r3[j];
        if (j == i) val = -INFINITY;   // diag mask (== reference's -1e6)
        v[q] = val; id[q] = j;
    }
    int mine = -1;
    for (int k = 0; k < TOPK; k++) {
        float bv = -INFINITY; int bi = NN;
#pragma unroll
        for (int q = 0; q < 6; q++) {
            if (v[q] > bv || (v[q] == bv && id[q] < bi)) { bv = v[q]; bi = id[q]; }
        }
        for (int off = 32; off > 0; off >>= 1) {
            float ov = __shfl_down(bv, off);
            int   oi = __shfl_down(bi, off);
            if (ov > bv || (ov == bv && oi < bi)) { bv = ov; bi = oi; }
        }
        bi = __shfl(bi, 0);
        if (t == k) mine = bi;
#pragma unroll
        for (int q = 0; q < 6; q++) if (id[q] == bi) v[q] = -INFINITY;
    }
    if (t < TOPK) {
        int tg = b * NN + mine;
        int q = atomicAdd(&counts[tg], 1);
        inlist[(size_t)tg * CAP + q] = i;
    } else if (t == TOPK) {          // self loop
        int q = atomicAdd(&counts[row], 1);
        inlist[(size_t)row * CAP + q] = i;
    }
}

// ---------------- GAT1 aggregation: ONE block per node (512 thr), all 4 heads, no atomics ----------------
__global__ __launch_bounds__(512) void k_agg1(const int* __restrict__ counts,
        const int* __restrict__ inlist, const float* __restrict__ a_s,
        const float* __restrict__ a_d, const float* __restrict__ xw1,
        const float* __restrict__ gat1_b, const float* __restrict__ w2,
        float* __restrict__ xw2) {
    __shared__ int slist[CAP];
    __shared__ float walpha[NHEADS][CAP];
    __shared__ float redp[16];
    int node = blockIdx.x;
    int b = node / NN;
    int t = threadIdx.x;
    int wid = t >> 6;
    int lane = t & 63;
    int deg = counts[node];
    for (int e = t; e < deg; e += 512) slist[e] = inlist[(size_t)node * CAP + e];
    __syncthreads();
    if (t < 256) {                   // waves 0..3: softmax for head = wid (same FP order as before)
        int h = wid;
        float ad = a_d[(size_t)node * NHEADS + h];
        float vals[7];
        int cnt = 0;
        float vmax = -INFINITY;
        for (int e = lane; e < deg; e += 64) {
            float x = a_s[(size_t)(b * NN + slist[e]) * NHEADS + h] + ad;
            x = x >= 0.f ? x : NEG * x;
            vals[cnt++] = x;
            vmax = fmaxf(vmax, x);
        }
#pragma unroll
        for (int off = 32; off > 0; off >>= 1)
            vmax = fmaxf(vmax, __shfl_xor(vmax, off));
        float sum = 0.f;
        for (int i = 0; i < cnt; i++) {
            vals[i] = expf(vals[i] - vmax);
            sum += vals[i];
        }
#pragma unroll
        for (int off = 32; off > 0; off >>= 1)
            sum += __shfl_xor(sum, off);
        float inv = 1.f / fmaxf(sum, 1e-16f);
        cnt = 0;
        for (int e = lane; e < deg; e += 64) walpha[h][e] = vals[cnt++] * inv;
    }
    __syncthreads();
    // gather: thread t handles d0 = t (heads 0/1), d1 = t+512 (heads 2/3)
    int d0 = t, d1 = t + 512;
    int h0 = d0 >> 8, h1 = d1 >> 8;
    float acc0 = 0.f, acc1 = 0.f;
    for (int e = 0; e < deg; e++) {
        const float* xr = xw1 + (size_t)(b * NN + slist[e]) * 1024;
        acc0 += walpha[h0][e] * xr[d0];
        acc1 += walpha[h1][e] * xr[d1];
    }
    float o0 = fmaxf(acc0 + gat1_b[d0], 0.f);
    float o1 = fmaxf(acc1 + gat1_b[d1], 0.f);
    float p0 = o0 * w2[d0 * 2]     + o1 * w2[d1 * 2];
    float p1v = o0 * w2[d0 * 2 + 1] + o1 * w2[d1 * 2 + 1];
#pragma unroll
    for (int off = 32; off > 0; off >>= 1) {
        p0 += __shfl_xor(p0, off);
        p1v += __shfl_xor(p1v, off);
    }
    if (lane == 0) { redp[wid] = p0; redp[8 + wid] = p1v; }
    __syncthreads();
    if (t == 0) {
        float s0 = 0.f, s1 = 0.f;
#pragma unroll
        for (int q = 0; q < 8; q++) { s0 += redp[q]; s1 += redp[8 + q]; }
        xw2[(size_t)node * 2]     = s0;
        xw2[(size_t)node * 2 + 1] = s1;
    }
}

// ---------------- GAT2 aggregation -> output (one wave per node; on-the-fly att dots) ----------------
__global__ __launch_bounds__(64) void k_agg2(const int* __restrict__ counts,
        const int* __restrict__ inlist, const float* __restrict__ xw2,
        const float* __restrict__ as2, const float* __restrict__ ad2,
        const float* __restrict__ b2, float* __restrict__ out) {
    int node = blockIdx.x;
    int b = node / NN;
    int lane = threadIdx.x;
    int deg = counts[node];
    float s0 = as2[0], s1 = as2[1];
    float d0 = ad2[0], d1 = ad2[1];
    float2 xwn = *(const float2*)(xw2 + (size_t)node * 2);
    float ad = xwn.x * d0 + xwn.y * d1;
    float vals[7], xs0[7], xs1[7];
    int cnt = 0;
    float vmax = -INFINITY;
    for (int e = lane; e < deg; e += 64) {
        int s = b * NN + inlist[(size_t)node * CAP + e];
        float2 xws = *(const float2*)(xw2 + (size_t)s * 2);
        float x = xws.x * s0 + xws.y * s1 + ad;
        x = x >= 0.f ? x : NEG * x;
        xs0[cnt] = xws.x; xs1[cnt] = xws.y; vals[cnt] = x; cnt++;
        vmax = fmaxf(vmax, x);
    }
#pragma unroll
    for (int off = 32; off > 0; off >>= 1)
        vmax = fmaxf(vmax, __shfl_xor(vmax, off));
    float sum = 0.f;
    for (int i = 0; i < cnt; i++) {
        vals[i] = expf(vals[i] - vmax);
        sum += vals[i];
    }
#pragma unroll
    for (int off = 32; off > 0; off >>= 1)
        sum += __shfl_xor(sum, off);
    float inv = 1.f / fmaxf(sum, 1e-16f);
    float a0 = 0.f, a1 = 0.f;
    for (int i = 0; i < cnt; i++) {
        a0 += vals[i] * xs0[i];
        a1 += vals[i] * xs1[i];
    }
#pragma unroll
    for (int off = 32; off > 0; off >>= 1) {
        a0 += __shfl_xor(a0, off);
        a1 += __shfl_xor(a1, off);
    }
    if (lane == 0) {
        out[(size_t)node * 2]     = a0 * inv + b2[0];
        out[(size_t)node * 2 + 1] = a1 * inv + b2[1];
    }
}

extern "C" void kernel_launch(void* const* d_in, const int* in_sizes, int n_in,
                              void* d_out, int out_size, void* d_ws, size_t ws_size,
                              hipStream_t stream) {
    const float* feats  = (const float*)d_in[0];
    const float* boxes  = (const float*)d_in[1];
    const float* fc1_w  = (const float*)d_in[2];
    const float* fc1_b  = (const float*)d_in[3];
    const float* fc2_w  = (const float*)d_in[4];
    const float* fc2_b  = (const float*)d_in[5];
    const float* gat1_w = (const float*)d_in[6];
    const float* g1as   = (const float*)d_in[7];
    const float* g1ad   = (const float*)d_in[8];
    const float* gat1_b = (const float*)d_in[9];
    const float* gat2_w = (const float*)d_in[10];
    const float* g2as   = (const float*)d_in[11];
    const float* g2ad   = (const float*)d_in[12];
    const float* gat2_b = (const float*)d_in[13];
    float* out = (float*)d_out;
    (void)fc2_b;   // constant offset: order-irrelevant for top-k; GAT consumes edges only

    char* ws = (char*)d_ws;
    size_t off = 0;
    auto alloc = [&](size_t bytes) -> void* {
        void* p = ws + off;
        off += (bytes + 255) / 256 * 256;
        return p;
    };
    int*   counts = (int*)alloc((size_t)BB * NN * 4);
    int*   inlist = (int*)alloc((size_t)BB * NN * CAP * 4);
    float* p1     = (float*)alloc((size_t)BB * NN * HR * 4);
    float* p2t    = (float*)alloc((size_t)BB * HR * NN * 4);
    float* relq   = (float*)alloc((size_t)4 * BB * NN * NN * 4);
    float* xw1    = (float*)alloc((size_t)BB * NN * 1024 * 4);
    float* a_s1   = (float*)alloc((size_t)BB * NN * NHEADS * 4);
    float* a_d1   = (float*)alloc((size_t)BB * NN * NHEADS * 4);
    float* xw2    = (float*)alloc((size_t)BB * NN * 2 * 4);
    uint4* Asw    = (uint4*)alloc((size_t)48 * 33 * 64 * 16);
    uint4* Bsw    = (uint4*)alloc((size_t)64 * 33 * 64 * 16);
    uint4* Ah     = (uint4*)alloc((size_t)48 * 32 * 64 * 16);
    uint4* Al     = (uint4*)alloc((size_t)48 * 32 * 64 * 16);
    uint4* Bh     = (uint4*)alloc((size_t)32 * 32 * 64 * 16);
    uint4* Bl     = (uint4*)alloc((size_t)32 * 32 * 64 * 16);
    float4* wgp   = (float4*)alloc((size_t)HR * 16);
    (void)ws_size; (void)in_sizes; (void)n_in; (void)out_size;

    k_prep<<<1565, 256, 0, stream>>>(feats, boxes, gat1_w, fc1_w,
                                     Asw, Bsw, Ah, Al, Bh, Bl, wgp, counts);
    k_mm<<<576, 512, 0, stream>>>(Ah, Al, Bh, Bl, fc1_b, p1, p2t, Asw, Bsw, xw1);
    k_relatt<<<1536, 384, 0, stream>>>(p1, p2t, boxes, wgp, fc2_w, relq,
                                       xw1, g1as, g1ad, a_s1, a_d1);
    k_topk_inv<<<BB * NN, 64, 0, stream>>>(relq, counts, inlist);
    k_agg1<<<BB * NN, 512, 0, stream>>>(counts, inlist, a_s1, a_d1, xw1,
                                        gat1_b, gat2_w, xw2);
    k_agg2<<<BB * NN, 64, 0, stream>>>(counts, inlist, xw2, g2as, g2ad, gat2_b, out);
}